// Round 9
// baseline (637.927 us; speedup 1.0000x reference)
//
#include <hip/hip_runtime.h>

using bf16x8 = __attribute__((ext_vector_type(8))) short;
using f32x4  = __attribute__((ext_vector_type(4))) float;
using f32x16 = __attribute__((ext_vector_type(16))) float;

static constexpr int EMB = 512, HEADS = 16, NTOK = 64, BWIN = 2048;
static constexpr int MROWS = BWIN * NTOK;   // 131072
static constexpr int QKVN  = 3 * EMB;       // 1536

__device__ __forceinline__ float bf2f(unsigned int u) {
  union { unsigned int i; float f; } c; c.i = u << 16; return c.f;
}
__device__ __forceinline__ unsigned short f2bf(float x) {
  union { float f; unsigned int i; } c; c.f = x;
  return (unsigned short)((c.i + 0x7fffu + ((c.i >> 16) & 1u)) >> 16);
}
__device__ __forceinline__ void gload_lds16(const void* g, void* l) {
  __builtin_amdgcn_global_load_lds((const __attribute__((address_space(1))) void*)g,
                                   (__attribute__((address_space(3))) void*)l, 16, 0, 0);
}
__device__ __forceinline__ unsigned int cvt_pk_bf16(float lo, float hi) {
  unsigned int d;
  asm("v_cvt_pk_bf16_f32 %0, %1, %2" : "=v"(d) : "v"(lo), "v"(hi));
  return d;
}

#define BARRIER() __builtin_amdgcn_s_barrier()
#define SCHED0()  __builtin_amdgcn_sched_barrier(0)
#define LGKM0()  do { asm volatile("s_waitcnt lgkmcnt(0)" ::: "memory"); \
                      __builtin_amdgcn_sched_barrier(0); } while (0)
#define VMCNT2() do { asm volatile("s_waitcnt vmcnt(2)" ::: "memory"); \
                      __builtin_amdgcn_sched_barrier(0); } while (0)
#define VMCNT4() do { asm volatile("s_waitcnt vmcnt(4)" ::: "memory"); \
                      __builtin_amdgcn_sched_barrier(0); } while (0)
#define VMCNT8() do { asm volatile("s_waitcnt vmcnt(8)" ::: "memory"); \
                      __builtin_amdgcn_sched_barrier(0); } while (0)

// ---------------- prep: weights -> bf16, build fused qkv bias ----------------
__global__ void prep_weights(const float* __restrict__ qkv_w, const float* __restrict__ proj_w,
                             const float* __restrict__ q_bias, const float* __restrict__ v_bias,
                             unsigned short* __restrict__ wq, unsigned short* __restrict__ wp,
                             float* __restrict__ qkv_bias) {
  int i = blockIdx.x * 256 + threadIdx.x;          // grid covers 786432 = |qkv_w|
  wq[i] = f2bf(qkv_w[i]);
  if (i < EMB * EMB) wp[i] = f2bf(proj_w[i]);
  if (i < EMB) {
    qkv_bias[i]           = q_bias[i];
    qkv_bias[EMB + i]     = 0.f;                   // k bias is zero in reference
    qkv_bias[2 * EMB + i] = v_bias[i];
  }
}

// ---------------- CPB MLP: 225 positions -> (225,16) raw logits ----------------
__global__ __launch_bounds__(64) void cpb_mlp(const float* __restrict__ tbl,
                        const float* __restrict__ w1, const float* __restrict__ b1,
                        const float* __restrict__ w2, float* __restrict__ tab) {
  __shared__ float hid[512];
  const int p = blockIdx.x, t = threadIdx.x;
  const float t0 = tbl[p * 2], t1 = tbl[p * 2 + 1];
  #pragma unroll
  for (int s = 0; s < 8; ++s) {
    int j = t + s * 64;
    hid[j] = fmaxf(0.f, t0 * w1[j * 2] + t1 * w1[j * 2 + 1] + b1[j]);
  }
  __syncthreads();
  const int h = t >> 2, q = t & 3;
  float sum = 0.f;
  for (int j = q * 128; j < q * 128 + 128; ++j) sum += hid[j] * w2[h * 512 + j];
  sum += __shfl_xor(sum, 1);
  sum += __shfl_xor(sum, 2);
  if (q == 0) tab[p * 16 + h] = sum;
}

// ------- expand TRANSPOSED: biasT[h][kk][q] = 16*sigmoid(tab[rel_index[q][kk]][h]) -------
__global__ void cpb_expand(const float* __restrict__ tab, const int* __restrict__ rel_index,
                           float* __restrict__ biasT) {
  int e = blockIdx.x * 256 + threadIdx.x;   // 65536 total
  int h = e >> 12, ij = e & 4095;
  int kk = ij >> 6, q = ij & 63;
  float x = tab[rel_index[q * 64 + kk] * 16 + h];
  biasT[e] = 16.f / (1.f + __expf(-x));
}

// ---- 256x256 8-phase NT GEMM, fp32 A (reg-staged cvt), bf16 out ----
// R9 change: AW (cvt + swizzled ds_write) moved AFTER mfmaQ — out of the
// pre-MFMA LGKM0 drain path. Its write is drained by the NEXT phase's LGKM0,
// one phase before the earliest consumer (>=3 phases away). WAR safety
// unchanged (overwritten region's last reads drained >=2 barriers earlier).
template<int NBX, int KT>
__global__ __launch_bounds__(512, 2) void gemm256_af32(const float* __restrict__ Af,
    const unsigned short* __restrict__ Bp, const float* __restrict__ bias,
    unsigned short* __restrict__ Cp, int M, int N) {
  __shared__ unsigned short As[2][256 * 64];
  __shared__ unsigned short Bs[2][256 * 64];
  constexpr int NT = KT / 64;
  constexpr int NITER = NT / 2;
  const int t = threadIdx.x;
  const int l = t & 63, w = t >> 6;
  const int lr = l & 15, lg = l >> 4;
  const int q8 = gridDim.x >> 3;
  const int wgid = (blockIdx.x & 7) * q8 + (blockIdx.x >> 3);
  const int n0 = (wgid % NBX) * 256, m0 = (wgid / NBX) * 256;
  const int wm = (w >> 2) * 128, wn = (w & 3) * 64;
  const int ha128 = (w >> 2) * 128;
  const int srow = t >> 3;
  const int scol = ((t & 7) ^ (srow & 7)) << 3;        // B inverse-swizzled src col
  const int arow = t >> 2, aq = t & 3;                 // A: row in half, 16-elem quarter
  const float* Ab = Af + (size_t)m0 * KT;
  const unsigned short* Bbase = Bp + (size_t)n0 * KT;

  f32x4 acc[8][4];
  #pragma unroll
  for (int i = 0; i < 8; ++i)
    #pragma unroll
    for (int j = 0; j < 4; ++j) acc[i][j] = (f32x4){0.f, 0.f, 0.f, 0.f};
  bf16x8 afr[4][2], bfr[4][2];
  float4 rC0[4], rC1[4], rN0[4], rN1[4], rD0[4], rD1[4];

  auto BS = [&](int d, int kt, int half) {             // B half via gload_lds
    const unsigned short* g = Bbase + (size_t)(half * 128 + srow) * KT + kt * 64 + scol;
    unsigned short* lds = &Bs[d][0] + half * 8192 + w * 512;
    gload_lds16(g, lds);
    gload_lds16(g + (size_t)64 * KT, lds + 4096);
  };
  auto AL = [&](int kt, int half, float4* R) {         // issue A quarter-row loads
    const float* g = Ab + (size_t)(half * 128 + arow) * KT + kt * 64 + aq * 16;
    R[0] = ((const float4*)g)[0]; R[1] = ((const float4*)g)[1];
    R[2] = ((const float4*)g)[2]; R[3] = ((const float4*)g)[3];
  };
  auto AW = [&](int d, int half, const float4* R) {    // cvt + swizzled ds_write
    unsigned short* dst = &As[d][(half * 128 + arow) * 64];
    const float* f = (const float*)R;
    unsigned int dw[8];
    #pragma unroll
    for (int m2 = 0; m2 < 8; ++m2) dw[m2] = cvt_pk_bf16(f[2 * m2], f[2 * m2 + 1]);
    union { uint4 u; bf16x8 v; } lo, hi;
    lo.u = make_uint4(dw[0], dw[1], dw[2], dw[3]);
    hi.u = make_uint4(dw[4], dw[5], dw[6], dw[7]);
    const int r7 = arow & 7;
    *(bf16x8*)(dst + ((aq * 2) ^ r7) * 8)     = lo.v;
    *(bf16x8*)(dst + ((aq * 2 + 1) ^ r7) * 8) = hi.v;
  };
  auto ldA4 = [&](int d, int mb) {
    #pragma unroll
    for (int m = 0; m < 4; ++m) {
      int row = ha128 + (mb + m) * 16 + lr;
      #pragma unroll
      for (int ks = 0; ks < 2; ++ks)
        afr[m][ks] = *(const bf16x8*)(&As[d][row * 64 + ((((ks << 2) + lg) ^ (lr & 7)) << 3)]);
    }
  };
  auto ldB2 = [&](int d, int nb) {
    #pragma unroll
    for (int n = 0; n < 2; ++n) {
      int row = wn + (nb + n) * 16 + lr;
      #pragma unroll
      for (int ks = 0; ks < 2; ++ks)
        bfr[nb + n][ks] = *(const bf16x8*)(&Bs[d][row * 64 + ((((ks << 2) + lg) ^ (lr & 7)) << 3)]);
    }
  };
  auto mfmaQ = [&](int mb, int nb) {
    __builtin_amdgcn_s_setprio(1);
    #pragma unroll
    for (int ks = 0; ks < 2; ++ks)
      #pragma unroll
      for (int m = 0; m < 4; ++m)
        #pragma unroll
        for (int n = 0; n < 2; ++n)
          acc[mb + m][nb + n] = __builtin_amdgcn_mfma_f32_16x16x32_bf16(
              afr[m][ks], bfr[nb + n][ks], acc[mb + m][nb + n], 0, 0, 0);
    __builtin_amdgcn_s_setprio(0);
  };

  // ---- prologue: T0 fully into d0 (A via reg-cvt); T1's A loads in flight ----
  AL(0, 0, rN0); AL(0, 1, rN1); SCHED0();
  BS(0, 0, 0); BS(0, 0, 1); SCHED0();
  AW(0, 0, rN0); AW(0, 1, rN1); SCHED0();              // compiler drains AL kt0
  AL((NT > 1 ? 1 : 0), 0, rC0); AL((NT > 1 ? 1 : 0), 1, rC1); SCHED0();
  VMCNT8();                                            // BS kt0 landed (8 A-loads fly)
  LGKM0();
  BARRIER();

  #pragma unroll
  for (int i = 0; i < NITER; ++i) {
    const int ktb = 2 * i + 1;
    const int ktc = (2 * i + 2 < NT) ? 2 * i + 2 : NT - 1;   // clamped tail (dead)
    const int ktd = (2 * i + 3 < NT) ? 2 * i + 3 : NT - 1;
    // PH1: ds d0 (A mf0-3, B nf0-1); post-MFMA: write d1-Ah0 from carried regs
    ldA4(0, 0); ldB2(0, 0);
    BARRIER(); LGKM0(); mfmaQ(0, 0);
    AW(1, 0, rC0); SCHED0();
    BARRIER();
    // PH2: ds d0 (B nf2-3); stage d1-Bh0; issue A(ktc,h0); post-MFMA: write d1-Ah1
    ldB2(0, 2);
    BS(1, ktb, 0); SCHED0();
    AL(ktc, 0, rN0); SCHED0();
    BARRIER(); LGKM0(); mfmaQ(0, 2);
    AW(1, 1, rC1); SCHED0();
    BARRIER();
    // PH3: ds d0 (A mf4-7); stage d1-Bh1; issue A(ktc,h1)
    ldA4(0, 4);
    BS(1, ktb, 1); SCHED0();
    AL(ktc, 1, rN1); SCHED0();
    BARRIER(); LGKM0(); mfmaQ(4, 2); BARRIER();
    // PH4: GATE vmcnt(4): d1's B halves landed (A(ktc,h1) stays in flight)
    VMCNT4(); BARRIER(); mfmaQ(4, 0); BARRIER();
    // PH5: ds d1 (A mf0-3, B nf0-1); post-MFMA: write d0-Ah0 (regs drained at G1)
    ldA4(1, 0); ldB2(1, 0);
    BARRIER(); LGKM0(); mfmaQ(0, 0);
    AW(0, 0, rN0); SCHED0();
    BARRIER();
    // PH6: ds d1 (B nf2-3); stage d0-Bh0; issue A(ktd,h0); post-MFMA: write d0-Ah1
    ldB2(1, 2);
    BS(0, ktc, 0); SCHED0();
    AL(ktd, 0, rD0); SCHED0();
    BARRIER(); LGKM0(); mfmaQ(0, 2);
    AW(0, 1, rN1); SCHED0();
    BARRIER();
    // PH7: ds d1 (A mf4-7); stage d0-Bh1; issue A(ktd,h1)
    ldA4(1, 4);
    BS(0, ktc, 1); SCHED0();
    AL(ktd, 1, rD1); SCHED0();
    BARRIER(); LGKM0(); mfmaQ(4, 2); BARRIER();
    // PH8: GATE vmcnt(4): d0's B halves landed (A(ktd,h1) stays in flight)
    VMCNT4(); BARRIER(); mfmaQ(4, 0); BARRIER();
    #pragma unroll
    for (int j = 0; j < 4; ++j) { rC0[j] = rD0[j]; rC1[j] = rD1[j]; }
  }

  // ---- epilogue: C = acc + bias (bf16 out) ----
  #pragma unroll
  for (int mf = 0; mf < 8; ++mf)
    #pragma unroll
    for (int nf = 0; nf < 4; ++nf)
      #pragma unroll
      for (int r = 0; r < 4; ++r) {
        int mm = m0 + wm + mf * 16 + lg * 4 + r;
        int nn = n0 + wn + nf * 16 + lr;
        Cp[(size_t)mm * N + nn] = f2bf(acc[mf][nf][r] + bias[nn]);
      }
}

// ---------------- 256x256 8-phase NT GEMM, bf16 A (R4 verbatim) — proj ----------------
template<bool OUT_F32, int NBX, int KT>
__global__ __launch_bounds__(512, 2) void gemm256(const unsigned short* __restrict__ Ap,
    const unsigned short* __restrict__ Bp, const float* __restrict__ bias,
    void* __restrict__ Cp, int M, int N) {
  __shared__ unsigned short As[2][256 * 64];
  __shared__ unsigned short Bs[2][256 * 64];
  constexpr int NT = KT / 64;
  constexpr int NITER = NT / 2;
  const int t = threadIdx.x;
  const int l = t & 63, w = t >> 6;
  const int lr = l & 15, lg = l >> 4;
  const int q8 = gridDim.x >> 3;
  const int wgid = (blockIdx.x & 7) * q8 + (blockIdx.x >> 3);
  const int n0 = (wgid % NBX) * 256, m0 = (wgid / NBX) * 256;
  const int wm = (w >> 2) * 128, wn = (w & 3) * 64;
  const int ha128 = (w >> 2) * 128;
  const int srow = t >> 3;
  const int scol = ((t & 7) ^ (srow & 7)) << 3;
  const unsigned short* Abase = Ap + (size_t)m0 * KT;
  const unsigned short* Bbase = Bp + (size_t)n0 * KT;

  f32x4 acc[8][4];
  #pragma unroll
  for (int i = 0; i < 8; ++i)
    #pragma unroll
    for (int j = 0; j < 4; ++j) acc[i][j] = (f32x4){0.f, 0.f, 0.f, 0.f};
  bf16x8 afr[4][2], bfr[4][2];

  auto stage_half = [&](int d, int kt, int half, bool isA) {
    const unsigned short* g = (isA ? Abase : Bbase)
        + (size_t)(half * 128 + srow) * KT + kt * 64 + scol;
    unsigned short* lds = (isA ? &As[d][0] : &Bs[d][0]) + half * 8192 + (t >> 6) * 512;
    gload_lds16(g, lds);
    gload_lds16(g + (size_t)64 * KT, lds + 4096);
  };
  auto ldA4 = [&](int d, int mb) {
    #pragma unroll
    for (int m = 0; m < 4; ++m) {
      int row = ha128 + (mb + m) * 16 + lr;
      #pragma unroll
      for (int ks = 0; ks < 2; ++ks)
        afr[m][ks] = *(const bf16x8*)(&As[d][row * 64 + ((((ks << 2) + lg) ^ (lr & 7)) << 3)]);
    }
  };
  auto ldB2 = [&](int d, int nb) {
    #pragma unroll
    for (int n = 0; n < 2; ++n) {
      int row = wn + (nb + n) * 16 + lr;
      #pragma unroll
      for (int ks = 0; ks < 2; ++ks)
        bfr[nb + n][ks] = *(const bf16x8*)(&Bs[d][row * 64 + ((((ks << 2) + lg) ^ (lr & 7)) << 3)]);
    }
  };
  auto mfmaQ = [&](int mb, int nb) {
    __builtin_amdgcn_s_setprio(1);
    #pragma unroll
    for (int ks = 0; ks < 2; ++ks)
      #pragma unroll
      for (int m = 0; m < 4; ++m)
        #pragma unroll
        for (int n = 0; n < 2; ++n)
          acc[mb + m][nb + n] = __builtin_amdgcn_mfma_f32_16x16x32_bf16(
              afr[m][ks], bfr[nb + n][ks], acc[mb + m][nb + n], 0, 0, 0);
    __builtin_amdgcn_s_setprio(0);
  };

  stage_half(0, 0, 0, true);  stage_half(0, 0, 1, true);
  stage_half(0, 0, 0, false); stage_half(0, 0, 1, false);
  stage_half(1, (NT > 1 ? 1 : 0), 0, true);
  VMCNT2();
  BARRIER();

  for (int i = 0; i < NITER; ++i) {
    const int kt1 = 2 * i + 1;
    const int kt2 = (2 * i + 2 < NT) ? 2 * i + 2 : NT - 1;
    const int kt3 = (2 * i + 3 < NT) ? 2 * i + 3 : NT - 1;
    ldA4(0, 0); ldB2(0, 0);
    stage_half(1, kt1, 1, true);
    BARRIER(); LGKM0(); mfmaQ(0, 0); BARRIER();
    ldB2(0, 2);
    stage_half(1, kt1, 0, false);
    BARRIER(); LGKM0(); mfmaQ(0, 2); BARRIER();
    ldA4(0, 4);
    stage_half(1, kt1, 1, false);
    BARRIER(); LGKM0(); mfmaQ(4, 2); BARRIER();
    stage_half(0, kt2, 0, true);
    VMCNT2(); BARRIER(); mfmaQ(4, 0); BARRIER();
    ldA4(1, 0); ldB2(1, 0);
    stage_half(0, kt2, 1, true);
    BARRIER(); LGKM0(); mfmaQ(0, 0); BARRIER();
    ldB2(1, 2);
    stage_half(0, kt2, 0, false);
    BARRIER(); LGKM0(); mfmaQ(0, 2); BARRIER();
    ldA4(1, 4);
    stage_half(0, kt2, 1, false);
    BARRIER(); LGKM0(); mfmaQ(4, 2); BARRIER();
    stage_half(1, kt3, 0, true);
    VMCNT2(); BARRIER(); mfmaQ(4, 0); BARRIER();
  }

  #pragma unroll
  for (int mf = 0; mf < 8; ++mf)
    #pragma unroll
    for (int nf = 0; nf < 4; ++nf)
      #pragma unroll
      for (int r = 0; r < 4; ++r) {
        int mm = m0 + wm + mf * 16 + lg * 4 + r;
        int nn = n0 + wn + nf * 16 + lr;
        float v = acc[mf][nf][r] + bias[nn];
        if (OUT_F32) ((float*)Cp)[(size_t)mm * N + nn] = v;
        else ((unsigned short*)Cp)[(size_t)mm * N + nn] = f2bf(v);
      }
}

// ------------- fused window attention v3: 32x32 MFMA, in-reg softmax, low-VGPR -------------
// R9 changes vs v2: (a) no bv preload (vT read inside PV loop, -16 VGPR);
// (b) deferred normalization: exp values packed to bf16 inline during the sum
// loop (shorter p live range, no 32 muls); 1/sum written to invLds[64] and
// applied at the O store via broadcast ds_read (uniform addr per r -> free).
// (c) __launch_bounds__(64, 4): 4 waves/SIMD for latency hiding.
__global__ __launch_bounds__(64, 4) void attn_win(const unsigned short* __restrict__ qkv,
    const float* __restrict__ biasT, const float* __restrict__ flex,
    unsigned short* __restrict__ aout) {
  __shared__ __align__(16) unsigned short vT[32 * 64];   // 4KB, XOR-swizzled 16B slots
  __shared__ float invLds[64];
  const int l = threadIdx.x;
  const int lq = l & 31, hi = l >> 5;
  const int g = (blockIdx.x & 7) * (gridDim.x >> 3) + (blockIdx.x >> 3);
  const int b = g >> 4;
  const int h = g & 15;
  const unsigned short* base = qkv + (size_t)b * NTOK * QKVN;
  const float scale = __expf(fminf(flex[h], 4.6051701860f));

  {
    const uint4* vp = (const uint4*)(base + (size_t)l * QKVN + 2 * EMB + h * 32);
    uint4 v0 = vp[0], v1 = vp[1], v2 = vp[2], v3 = vp[3];
    unsigned int wd[16] = {v0.x, v0.y, v0.z, v0.w, v1.x, v1.y, v1.z, v1.w,
                           v2.x, v2.y, v2.z, v2.w, v3.x, v3.y, v3.z, v3.w};
    #pragma unroll
    for (int d = 0; d < 32; ++d) {
      unsigned short val = (d & 1) ? (unsigned short)(wd[d >> 1] >> 16)
                                   : (unsigned short)(wd[d >> 1] & 0xffffu);
      vT[d * 64 + (((l >> 3) ^ (d & 7)) << 3) + (l & 7)] = val;
    }
  }

  bf16x8 kfr[2][2], qfr[2][2];
  #pragma unroll
  for (int f = 0; f < 2; ++f) {
    #pragma unroll
    for (int which = 0; which < 2; ++which) {
      const unsigned short* rp = base + (size_t)(f * 32 + lq) * QKVN
                               + (which ? 0 : EMB) + h * 32 + hi * 8;
      uint4 r0 = *(const uint4*)rp;
      uint4 r1 = *(const uint4*)(rp + 16);
      unsigned int wd[8] = {r0.x, r0.y, r0.z, r0.w, r1.x, r1.y, r1.z, r1.w};
      float fv[16];
      #pragma unroll
      for (int e = 0; e < 8; ++e) {
        fv[2 * e]     = bf2f(wd[e] & 0xffffu);
        fv[2 * e + 1] = bf2f(wd[e] >> 16);
      }
      float ss = 0.f;
      #pragma unroll
      for (int e = 0; e < 16; ++e) ss += fv[e] * fv[e];
      ss += __shfl_xor(ss, 32);
      float inv = (which ? scale : 1.f) / fmaxf(sqrtf(ss), 1e-12f);
      bf16x8 f0, f1;
      #pragma unroll
      for (int e = 0; e < 8; ++e) {
        f0[e] = (short)f2bf(fv[e] * inv);
        f1[e] = (short)f2bf(fv[8 + e] * inv);
      }
      if (which) { qfr[f][0] = f0; qfr[f][1] = f1; }
      else       { kfr[f][0] = f0; kfr[f][1] = f1; }
    }
  }

  asm volatile("" ::: "memory");                 // vT writes precede vT reads below

  const f32x16 z16 = (f32x16)(0.f);

  #pragma unroll
  for (int qf = 0; qf < 2; ++qf) {
    f32x16 s0 = __builtin_amdgcn_mfma_f32_32x32x16_bf16(kfr[0][0], qfr[qf][0], z16, 0, 0, 0);
    s0 = __builtin_amdgcn_mfma_f32_32x32x16_bf16(kfr[0][1], qfr[qf][1], s0, 0, 0, 0);
    f32x16 s1 = __builtin_amdgcn_mfma_f32_32x32x16_bf16(kfr[1][0], qfr[qf][0], z16, 0, 0, 0);
    s1 = __builtin_amdgcn_mfma_f32_32x32x16_bf16(kfr[1][1], qfr[qf][1], s1, 0, 0, 0);

    float p[32];
    const float* bt = biasT + (size_t)h * 4096 + qf * 32 + lq;
    #pragma unroll
    for (int r = 0; r < 16; ++r) {
      int kkb = (r & 3) + 8 * (r >> 2) + 4 * hi;
      p[r]      = s0[r] + bt[kkb * 64];
      p[16 + r] = s1[r] + bt[(32 + kkb) * 64];
    }
    float mx = p[0];
    #pragma unroll
    for (int e = 1; e < 32; ++e) mx = fmaxf(mx, p[e]);
    mx = fmaxf(mx, __shfl_xor(mx, 32));
    // exp + inline bf16 pack (UNNORMALIZED); sum accumulated alongside
    float sum = 0.f;
    unsigned int wp_[2][8];
    #pragma unroll
    for (int kf = 0; kf < 2; ++kf)
      #pragma unroll
      for (int m = 0; m < 8; ++m) {
        float e0 = __expf(p[kf * 16 + 2 * m]     - mx);
        float e1 = __expf(p[kf * 16 + 2 * m + 1] - mx);
        sum += e0 + e1;
        wp_[kf][m] = cvt_pk_bf16(e0, e1);
      }
    sum += __shfl_xor(sum, 32);
    if (hi == 0) invLds[qf * 32 + lq] = 1.f / sum;   // per-q row sum (q = lq)
    asm volatile("" ::: "memory");

    unsigned int sw[2][8];
    #pragma unroll
    for (int kf = 0; kf < 2; ++kf)
      #pragma unroll
      for (int m = 0; m < 8; ++m)
        sw[kf][m] = (unsigned int)__builtin_amdgcn_ds_bpermute(
                        ((l ^ 32) & 63) << 2, (int)wp_[kf][m]);
    f32x16 oacc = z16;
    #pragma unroll
    for (int c = 0; c < 4; ++c) {
      const int kf = c >> 1, mlo = (c & 1) * 4;
      unsigned int d0 = hi ? sw[kf][mlo + 2] : wp_[kf][mlo + 0];
      unsigned int d1 = hi ? sw[kf][mlo + 3] : wp_[kf][mlo + 1];
      unsigned int d2 = hi ? wp_[kf][mlo + 2] : sw[kf][mlo + 0];
      unsigned int d3 = hi ? wp_[kf][mlo + 3] : sw[kf][mlo + 1];
      union { uint4 u; bf16x8 v; } pa;
      pa.u = make_uint4(d0, d1, d2, d3);
      bf16x8 bvv = *(const bf16x8*)(&vT[lq * 64 + ((((2 * c + hi) ^ (lq & 7))) << 3)]);
      oacc = __builtin_amdgcn_mfma_f32_32x32x16_bf16(pa.v, bvv, oacc, 0, 0, 0);
    }
    #pragma unroll
    for (int r = 0; r < 16; ++r) {
      int q = qf * 32 + (r & 3) + 8 * (r >> 2) + 4 * hi;
      float iv = invLds[q];                      // uniform addr per r -> broadcast
      aout[(size_t)(b * NTOK + q) * EMB + h * 32 + lq] = f2bf(oacc[r] * iv);
    }
  }
}

// ---------------- launch ----------------
extern "C" void kernel_launch(void* const* d_in, const int* in_sizes, int n_in,
                              void* d_out, int out_size, void* d_ws, size_t ws_size,
                              hipStream_t stream) {
  const float* x         = (const float*)d_in[0];
  const float* qkv_w     = (const float*)d_in[1];
  const float* q_bias    = (const float*)d_in[2];
  const float* v_bias    = (const float*)d_in[3];
  const float* flex      = (const float*)d_in[4];
  const float* cpb_w1    = (const float*)d_in[5];
  const float* cpb_b1    = (const float*)d_in[6];
  const float* cpb_w2    = (const float*)d_in[7];
  const float* proj_w    = (const float*)d_in[8];
  const float* proj_b    = (const float*)d_in[9];
  const float* rel_table = (const float*)d_in[10];
  const int*   rel_index = (const int*)d_in[11];

  char* ws = (char*)d_ws;
  unsigned short* qkv_bf = (unsigned short*)(ws + 0);                  // 402,653,184 B
  unsigned short* ao_bf  = (unsigned short*)(ws + 402653184ull);       // 134,217,728 B
  unsigned short* wq_bf  = (unsigned short*)(ws + 536870912ull);       //   1,572,864 B
  unsigned short* wp_bf  = (unsigned short*)(ws + 538443776ull);       //     524,288 B
  float* qkv_bias        = (float*)(ws + 538968064ull);                //       6,144 B
  float* tab             = (float*)(ws + 538974208ull);                //      14,400 B
  float* biasT           = (float*)(ws + 538988608ull);                //     262,144 B

  prep_weights<<<3072, 256, 0, stream>>>(qkv_w, proj_w, q_bias, v_bias, wq_bf, wp_bf, qkv_bias);
  cpb_mlp<<<225, 64, 0, stream>>>(rel_table, cpb_w1, cpb_b1, cpb_w2, tab);
  cpb_expand<<<256, 256, 0, stream>>>(tab, rel_index, biasT);
  // QKV (fp32 A read directly, xcast fused): grid 512*6 = 3072
  gemm256_af32<6, EMB><<<3072, 512, 0, stream>>>(
      x, wq_bf, qkv_bias, qkv_bf, MROWS, QKVN);
  attn_win<<<BWIN * HEADS, 64, 0, stream>>>(qkv_bf, biasT, flex, ao_bf);
  // proj: grid 512*2 = 1024
  gemm256<true, 2, EMB><<<1024, 512, 0, stream>>>(
      ao_bf, wp_bf, proj_b, d_out, MROWS, EMB);
}

// Round 12
// 637.833 us; speedup vs baseline: 1.0001x; 1.0001x over previous
//
#include <hip/hip_runtime.h>

using bf16x8 = __attribute__((ext_vector_type(8))) short;
using f32x4  = __attribute__((ext_vector_type(4))) float;
using f32x16 = __attribute__((ext_vector_type(16))) float;

static constexpr int EMB = 512, HEADS = 16, NTOK = 64, BWIN = 2048;
static constexpr int MROWS = BWIN * NTOK;   // 131072
static constexpr int QKVN  = 3 * EMB;       // 1536

__device__ __forceinline__ float bf2f(unsigned int u) {
  union { unsigned int i; float f; } c; c.i = u << 16; return c.f;
}
__device__ __forceinline__ unsigned short f2bf(float x) {
  union { float f; unsigned int i; } c; c.f = x;
  return (unsigned short)((c.i + 0x7fffu + ((c.i >> 16) & 1u)) >> 16);
}
__device__ __forceinline__ void gload_lds16(const void* g, void* l) {
  __builtin_amdgcn_global_load_lds((const __attribute__((address_space(1))) void*)g,
                                   (__attribute__((address_space(3))) void*)l, 16, 0, 0);
}
__device__ __forceinline__ unsigned int cvt_pk_bf16(float lo, float hi) {
  unsigned int d;
  asm("v_cvt_pk_bf16_f32 %0, %1, %2" : "=v"(d) : "v"(lo), "v"(hi));
  return d;
}

#define BARRIER() __builtin_amdgcn_s_barrier()
#define LGKM0()  do { asm volatile("s_waitcnt lgkmcnt(0)" ::: "memory"); \
                      __builtin_amdgcn_sched_barrier(0); } while (0)
#define VMCNT2() do { asm volatile("s_waitcnt vmcnt(2)" ::: "memory"); \
                      __builtin_amdgcn_sched_barrier(0); } while (0)

// ---------------- xcast: x (fp32) -> bf16, one shot ----------------
__global__ __launch_bounds__(256) void xcast(const float* __restrict__ x,
                                             unsigned short* __restrict__ xb) {
  size_t i = ((size_t)blockIdx.x * 256 + threadIdx.x) * 8;   // 32768 blocks cover 2^26 elems
  float4 a = *(const float4*)(x + i);
  float4 b = *(const float4*)(x + i + 4);
  ushort4 lo = make_ushort4(f2bf(a.x), f2bf(a.y), f2bf(a.z), f2bf(a.w));
  ushort4 hi = make_ushort4(f2bf(b.x), f2bf(b.y), f2bf(b.z), f2bf(b.w));
  *(ushort4*)(xb + i) = lo;
  *(ushort4*)(xb + i + 4) = hi;
}

// ---------------- prep: weights -> bf16, build fused qkv bias ----------------
__global__ void prep_weights(const float* __restrict__ qkv_w, const float* __restrict__ proj_w,
                             const float* __restrict__ q_bias, const float* __restrict__ v_bias,
                             unsigned short* __restrict__ wq, unsigned short* __restrict__ wp,
                             float* __restrict__ qkv_bias) {
  int i = blockIdx.x * 256 + threadIdx.x;          // grid covers 786432 = |qkv_w|
  wq[i] = f2bf(qkv_w[i]);
  if (i < EMB * EMB) wp[i] = f2bf(proj_w[i]);
  if (i < EMB) {
    qkv_bias[i]           = q_bias[i];
    qkv_bias[EMB + i]     = 0.f;                   // k bias is zero in reference
    qkv_bias[2 * EMB + i] = v_bias[i];
  }
}

// ---------------- CPB MLP: 225 positions -> (225,16) raw logits ----------------
__global__ __launch_bounds__(64) void cpb_mlp(const float* __restrict__ tbl,
                        const float* __restrict__ w1, const float* __restrict__ b1,
                        const float* __restrict__ w2, float* __restrict__ tab) {
  __shared__ float hid[512];
  const int p = blockIdx.x, t = threadIdx.x;
  const float t0 = tbl[p * 2], t1 = tbl[p * 2 + 1];
  #pragma unroll
  for (int s = 0; s < 8; ++s) {
    int j = t + s * 64;
    hid[j] = fmaxf(0.f, t0 * w1[j * 2] + t1 * w1[j * 2 + 1] + b1[j]);
  }
  __syncthreads();
  const int h = t >> 2, q = t & 3;
  float sum = 0.f;
  for (int j = q * 128; j < q * 128 + 128; ++j) sum += hid[j] * w2[h * 512 + j];
  sum += __shfl_xor(sum, 1);
  sum += __shfl_xor(sum, 2);
  if (q == 0) tab[p * 16 + h] = sum;
}

// ------- expand TRANSPOSED: biasT[h][kk][q] = 16*sigmoid(tab[rel_index[q][kk]][h]) -------
__global__ void cpb_expand(const float* __restrict__ tab, const int* __restrict__ rel_index,
                           float* __restrict__ biasT) {
  int e = blockIdx.x * 256 + threadIdx.x;   // 65536 total
  int h = e >> 12, ij = e & 4095;
  int kk = ij >> 6, q = ij & 63;
  float x = tab[rel_index[q * 64 + kk] * 16 + h];
  biasT[e] = 16.f / (1.f + __expf(-x));
}

// ---------------- 256x256 8-phase NT GEMM (R4 verbatim: 281us QKV, 6 passing runs) ----------------
template<bool OUT_F32, int NBX, int KT>
__global__ __launch_bounds__(512, 2) void gemm256(const unsigned short* __restrict__ Ap,
    const unsigned short* __restrict__ Bp, const float* __restrict__ bias,
    void* __restrict__ Cp, int M, int N) {
  __shared__ unsigned short As[2][256 * 64];
  __shared__ unsigned short Bs[2][256 * 64];
  constexpr int NT = KT / 64;          // K-tiles (8 for K=512)
  constexpr int NITER = NT / 2;
  const int t = threadIdx.x;
  const int l = t & 63, w = t >> 6;
  const int lr = l & 15, lg = l >> 4;
  const int q8 = gridDim.x >> 3;                       // gridDim.x % 8 == 0
  const int wgid = (blockIdx.x & 7) * q8 + (blockIdx.x >> 3);
  const int n0 = (wgid % NBX) * 256, m0 = (wgid / NBX) * 256;
  const int wm = (w >> 2) * 128, wn = (w & 3) * 64;    // wave's C offset in tile
  const int ha128 = (w >> 2) * 128;                    // wave's A half base row
  const int srow = t >> 3;
  const int scol = ((t & 7) ^ (srow & 7)) << 3;        // inverse-swizzled src col (elems)
  const unsigned short* Abase = Ap + (size_t)m0 * KT;
  const unsigned short* Bbase = Bp + (size_t)n0 * KT;

  f32x4 acc[8][4];
  #pragma unroll
  for (int i = 0; i < 8; ++i)
    #pragma unroll
    for (int j = 0; j < 4; ++j) acc[i][j] = (f32x4){0.f, 0.f, 0.f, 0.f};
  bf16x8 afr[4][2], bfr[4][2];

  auto stage_half = [&](int d, int kt, int half, bool isA) {
    const unsigned short* g = (isA ? Abase : Bbase)
        + (size_t)(half * 128 + srow) * KT + kt * 64 + scol;
    unsigned short* lds = (isA ? &As[d][0] : &Bs[d][0]) + half * 8192 + (t >> 6) * 512;
    gload_lds16(g, lds);                               // rows srow (w*8..w*8+7)
    gload_lds16(g + (size_t)64 * KT, lds + 4096);      // rows srow+64
  };
  auto ldA4 = [&](int d, int mb) {                     // afr <- A frags mb..mb+3, ks 0..1
    #pragma unroll
    for (int m = 0; m < 4; ++m) {
      int row = ha128 + (mb + m) * 16 + lr;
      #pragma unroll
      for (int ks = 0; ks < 2; ++ks)
        afr[m][ks] = *(const bf16x8*)(&As[d][row * 64 + ((((ks << 2) + lg) ^ (lr & 7)) << 3)]);
    }
  };
  auto ldB2 = [&](int d, int nb) {                     // bfr[nb..nb+1] <- B frags
    #pragma unroll
    for (int n = 0; n < 2; ++n) {
      int row = wn + (nb + n) * 16 + lr;
      #pragma unroll
      for (int ks = 0; ks < 2; ++ks)
        bfr[nb + n][ks] = *(const bf16x8*)(&Bs[d][row * 64 + ((((ks << 2) + lg) ^ (lr & 7)) << 3)]);
    }
  };
  auto mfmaQ = [&](int mb, int nb) {                   // 16 MFMA: one C quadrant, K=64
    __builtin_amdgcn_s_setprio(1);
    #pragma unroll
    for (int ks = 0; ks < 2; ++ks)
      #pragma unroll
      for (int m = 0; m < 4; ++m)
        #pragma unroll
        for (int n = 0; n < 2; ++n)
          acc[mb + m][nb + n] = __builtin_amdgcn_mfma_f32_16x16x32_bf16(
              afr[m][ks], bfr[nb + n][ks], acc[mb + m][nb + n], 0, 0, 0);
    __builtin_amdgcn_s_setprio(0);
  };

  // ---- prologue: T0 fully into d0, T1-Ah0 into d1 (mimics ph8 slot) ----
  stage_half(0, 0, 0, true);  stage_half(0, 0, 1, true);
  stage_half(0, 0, 0, false); stage_half(0, 0, 1, false);
  stage_half(1, (NT > 1 ? 1 : 0), 0, true);
  VMCNT2();                                            // T0's 8 loads landed
  BARRIER();

  for (int i = 0; i < NITER; ++i) {
    const int kt1 = 2 * i + 1;                         // always < NT
    const int kt2 = (2 * i + 2 < NT) ? 2 * i + 2 : NT - 1;   // clamped (tail garbage)
    const int kt3 = (2 * i + 3 < NT) ? 2 * i + 3 : NT - 1;
    // PH1: ds A(d0,mf0-3)+B(d0,nf0-1); stage d1<-T(kt1)-Ah1
    ldA4(0, 0); ldB2(0, 0);
    stage_half(1, kt1, 1, true);
    BARRIER(); LGKM0(); mfmaQ(0, 0); BARRIER();
    // PH2: ds B(d0,nf2-3); stage d1<-T(kt1)-Bh0
    ldB2(0, 2);
    stage_half(1, kt1, 0, false);
    BARRIER(); LGKM0(); mfmaQ(0, 2); BARRIER();
    // PH3: ds A(d0,mf4-7); stage d1<-T(kt1)-Bh1   (d0 fully consumed after this)
    ldA4(0, 4);
    stage_half(1, kt1, 1, false);
    BARRIER(); LGKM0(); mfmaQ(4, 2); BARRIER();
    // PH4: stage d0<-T(kt2)-Ah0; GATE vmcnt(2): T(kt1) all landed for ph5-8
    stage_half(0, kt2, 0, true);
    VMCNT2(); BARRIER(); mfmaQ(4, 0); BARRIER();
    // PH5: ds A(d1,mf0-3)+B(d1,nf0-1); stage d0<-T(kt2)-Ah1
    ldA4(1, 0); ldB2(1, 0);
    stage_half(0, kt2, 1, true);
    BARRIER(); LGKM0(); mfmaQ(0, 0); BARRIER();
    // PH6: ds B(d1,nf2-3); stage d0<-T(kt2)-Bh0
    ldB2(1, 2);
    stage_half(0, kt2, 0, false);
    BARRIER(); LGKM0(); mfmaQ(0, 2); BARRIER();
    // PH7: ds A(d1,mf4-7); stage d0<-T(kt2)-Bh1   (d1 fully consumed after this)
    ldA4(1, 4);
    stage_half(0, kt2, 1, false);
    BARRIER(); LGKM0(); mfmaQ(4, 2); BARRIER();
    // PH8: stage d1<-T(kt3)-Ah0; GATE vmcnt(2): T(kt2) all landed for next iter
    stage_half(1, kt3, 0, true);
    VMCNT2(); BARRIER(); mfmaQ(4, 0); BARRIER();
  }

  // ---- epilogue: C = acc + bias ----
  #pragma unroll
  for (int mf = 0; mf < 8; ++mf)
    #pragma unroll
    for (int nf = 0; nf < 4; ++nf)
      #pragma unroll
      for (int r = 0; r < 4; ++r) {
        int mm = m0 + wm + mf * 16 + lg * 4 + r;
        int nn = n0 + wn + nf * 16 + lr;
        float v = acc[mf][nf][r] + bias[nn];
        if (OUT_F32) ((float*)Cp)[(size_t)mm * N + nn] = v;
        else ((unsigned short*)Cp)[(size_t)mm * N + nn] = f2bf(v);
      }
}

// ------------- fused window attention v2 (R7 verbatim, 2 passing runs) -------------
// One wave per (window, head). Swapped QK^T: S^T = mfma(K, Q) puts q = lane&31 ->
// row-softmax = 31 fmax + 1 shfl_xor(32). P normalized in-register. P^T -> PV
// A-operand via cvt_pk_bf16 + ds_bpermute(l^32) + hi-select. LDS = 4KB vT only.
__global__ __launch_bounds__(64, 3) void attn_win(const unsigned short* __restrict__ qkv,
    const float* __restrict__ biasT, const float* __restrict__ flex,
    unsigned short* __restrict__ aout) {
  __shared__ __align__(16) unsigned short vT[32 * 64];   // 4KB, XOR-swizzled 16B slots
  const int l = threadIdx.x;                     // 0..63
  const int lq = l & 31, hi = l >> 5;
  // XCD-bijective swizzle (grid 32768 % 8 == 0): 16 heads of a window -> same XCD
  const int g = (blockIdx.x & 7) * (gridDim.x >> 3) + (blockIdx.x >> 3);
  const int b = g >> 4;
  const int h = g & 15;
  const unsigned short* base = qkv + (size_t)b * NTOK * QKVN;
  const float scale = __expf(fminf(flex[h], 4.6051701860f));   // min(flex, ln 100)

  // ---- V row (lane = tok) -> vT[d][tok], 16B-slot XOR swizzle ----
  {
    const uint4* vp = (const uint4*)(base + (size_t)l * QKVN + 2 * EMB + h * 32);
    uint4 v0 = vp[0], v1 = vp[1], v2 = vp[2], v3 = vp[3];
    unsigned int wd[16] = {v0.x, v0.y, v0.z, v0.w, v1.x, v1.y, v1.z, v1.w,
                           v2.x, v2.y, v2.z, v2.w, v3.x, v3.y, v3.z, v3.w};
    #pragma unroll
    for (int d = 0; d < 32; ++d) {
      unsigned short val = (d & 1) ? (unsigned short)(wd[d >> 1] >> 16)
                                   : (unsigned short)(wd[d >> 1] & 0xffffu);
      vT[d * 64 + (((l >> 3) ^ (d & 7)) << 3) + (l & 7)] = val;
    }
  }

  // ---- K and Q fragments (32x32x16 A/B layout), L2-normalized in-register ----
  bf16x8 kfr[2][2], qfr[2][2];                   // [tok-frag][d-chunk]
  #pragma unroll
  for (int f = 0; f < 2; ++f) {
    #pragma unroll
    for (int which = 0; which < 2; ++which) {    // 0 = K, 1 = Q
      const unsigned short* rp = base + (size_t)(f * 32 + lq) * QKVN
                               + (which ? 0 : EMB) + h * 32 + hi * 8;
      uint4 r0 = *(const uint4*)rp;              // d: hi*8 .. +8
      uint4 r1 = *(const uint4*)(rp + 16);       // d: 16+hi*8 ..
      unsigned int wd[8] = {r0.x, r0.y, r0.z, r0.w, r1.x, r1.y, r1.z, r1.w};
      float fv[16];
      #pragma unroll
      for (int e = 0; e < 8; ++e) {
        fv[2 * e]     = bf2f(wd[e] & 0xffffu);
        fv[2 * e + 1] = bf2f(wd[e] >> 16);
      }
      float ss = 0.f;
      #pragma unroll
      for (int e = 0; e < 16; ++e) ss += fv[e] * fv[e];
      ss += __shfl_xor(ss, 32);                  // partner holds the other 16 dims
      float inv = (which ? scale : 1.f) / fmaxf(sqrtf(ss), 1e-12f);
      bf16x8 f0, f1;
      #pragma unroll
      for (int e = 0; e < 8; ++e) {
        f0[e] = (short)f2bf(fv[e] * inv);        // d-chunk 0 (d = hi*8+e)
        f1[e] = (short)f2bf(fv[8 + e] * inv);    // d-chunk 1 (d = 16+hi*8+e)
      }
      if (which) { qfr[f][0] = f0; qfr[f][1] = f1; }
      else       { kfr[f][0] = f0; kfr[f][1] = f1; }
    }
  }

  asm volatile("" ::: "memory");                 // vT writes precede vT reads below

  // ---- vT B-fragments (shared by both q-halves): conflict-free swizzled b128 ----
  bf16x8 bv[4];
  #pragma unroll
  for (int c = 0; c < 4; ++c)
    bv[c] = *(const bf16x8*)(&vT[lq * 64 + ((((2 * c + hi) ^ (lq & 7))) << 3)]);

  const f32x16 z16 = (f32x16)(0.f);

  // ---- per q-half: QK^T (swapped) -> bias -> softmax -> pack -> PV -> store ----
  #pragma unroll
  for (int qf = 0; qf < 2; ++qf) {
    // S^T[kk][q]: kk-frag kf in rows, q = lane&31
    f32x16 s0 = __builtin_amdgcn_mfma_f32_32x32x16_bf16(kfr[0][0], qfr[qf][0], z16, 0, 0, 0);
    s0 = __builtin_amdgcn_mfma_f32_32x32x16_bf16(kfr[0][1], qfr[qf][1], s0, 0, 0, 0);
    f32x16 s1 = __builtin_amdgcn_mfma_f32_32x32x16_bf16(kfr[1][0], qfr[qf][0], z16, 0, 0, 0);
    s1 = __builtin_amdgcn_mfma_f32_32x32x16_bf16(kfr[1][1], qfr[qf][1], s1, 0, 0, 0);

    // p[kf*16+r] = S^T + biasT[h][kk][q],  kk = kf*32 + (r&3) + 8*(r>>2) + 4*hi
    float p[32];
    const float* bt = biasT + (size_t)h * 4096 + qf * 32 + lq;
    #pragma unroll
    for (int r = 0; r < 16; ++r) {
      int kkb = (r & 3) + 8 * (r >> 2) + 4 * hi;
      p[r]      = s0[r] + bt[kkb * 64];
      p[16 + r] = s1[r] + bt[(32 + kkb) * 64];
    }
    float mx = p[0];
    #pragma unroll
    for (int e = 1; e < 32; ++e) mx = fmaxf(mx, p[e]);
    mx = fmaxf(mx, __shfl_xor(mx, 32));
    float sum = 0.f;
    #pragma unroll
    for (int e = 0; e < 32; ++e) { p[e] = __expf(p[e] - mx); sum += p[e]; }
    sum += __shfl_xor(sum, 32);
    const float inv = 1.f / sum;
    #pragma unroll
    for (int e = 0; e < 32; ++e) p[e] *= inv;    // normalized P -> no O epilogue scale

    // pack kk-pairs to bf16 dwords; swap halves; assemble PV A-frags
    unsigned int wp_[2][8], sw[2][8];
    #pragma unroll
    for (int kf = 0; kf < 2; ++kf)
      #pragma unroll
      for (int m = 0; m < 8; ++m) {
        wp_[kf][m] = cvt_pk_bf16(p[kf * 16 + 2 * m], p[kf * 16 + 2 * m + 1]);
        sw[kf][m]  = (unsigned int)__builtin_amdgcn_ds_bpermute(
                        ((l ^ 32) & 63) << 2, (int)wp_[kf][m]);
      }
    f32x16 oacc = z16;
    #pragma unroll
    for (int c = 0; c < 4; ++c) {
      const int kf = c >> 1, mlo = (c & 1) * 4;
      unsigned int d0 = hi ? sw[kf][mlo + 2] : wp_[kf][mlo + 0];
      unsigned int d1 = hi ? sw[kf][mlo + 3] : wp_[kf][mlo + 1];
      unsigned int d2 = hi ? wp_[kf][mlo + 2] : sw[kf][mlo + 0];
      unsigned int d3 = hi ? wp_[kf][mlo + 3] : sw[kf][mlo + 1];
      union { uint4 u; bf16x8 v; } pa;
      pa.u = make_uint4(d0, d1, d2, d3);
      oacc = __builtin_amdgcn_mfma_f32_32x32x16_bf16(pa.v, bv[c], oacc, 0, 0, 0);
    }
    // O[q][d]: q = qf*32 + (r&3)+8*(r>>2)+4*hi, d = lane&31 (64B contiguous stores)
    #pragma unroll
    for (int r = 0; r < 16; ++r) {
      int q = qf * 32 + (r & 3) + 8 * (r >> 2) + 4 * hi;
      aout[(size_t)(b * NTOK + q) * EMB + h * 32 + lq] = f2bf(oacc[r]);
    }
  }
}

// ---------------- launch ----------------
extern "C" void kernel_launch(void* const* d_in, const int* in_sizes, int n_in,
                              void* d_out, int out_size, void* d_ws, size_t ws_size,
                              hipStream_t stream) {
  const float* x         = (const float*)d_in[0];
  const float* qkv_w     = (const float*)d_in[1];
  const float* q_bias    = (const float*)d_in[2];
  const float* v_bias    = (const float*)d_in[3];
  const float* flex      = (const float*)d_in[4];
  const float* cpb_w1    = (const float*)d_in[5];
  const float* cpb_b1    = (const float*)d_in[6];
  const float* cpb_w2    = (const float*)d_in[7];
  const float* proj_w    = (const float*)d_in[8];
  const float* proj_b    = (const float*)d_in[9];
  const float* rel_table = (const float*)d_in[10];
  const int*   rel_index = (const int*)d_in[11];

  char* ws = (char*)d_ws;
  unsigned short* qkv_bf = (unsigned short*)(ws + 0);                  // 402,653,184 B
  // xb (bf16 x) and ao_bf ALIAS: xb dies when the QKV GEMM finishes; ao_bf is
  // born at attn_win. Both are 134,217,728 B and fully rewritten every call.
  unsigned short* xb     = (unsigned short*)(ws + 402653184ull);
  unsigned short* ao_bf  = (unsigned short*)(ws + 402653184ull);
  unsigned short* wq_bf  = (unsigned short*)(ws + 536870912ull);       //   1,572,864 B
  unsigned short* wp_bf  = (unsigned short*)(ws + 538443776ull);       //     524,288 B
  float* qkv_bias        = (float*)(ws + 538968064ull);                //       6,144 B
  float* tab             = (float*)(ws + 538974208ull);                //      14,400 B
  float* biasT           = (float*)(ws + 538988608ull);                //     262,144 B

  xcast<<<32768, 256, 0, stream>>>(x, xb);
  prep_weights<<<3072, 256, 0, stream>>>(qkv_w, proj_w, q_bias, v_bias, wq_bf, wp_bf, qkv_bias);
  cpb_mlp<<<225, 64, 0, stream>>>(rel_table, cpb_w1, cpb_b1, cpb_w2, tab);
  cpb_expand<<<256, 256, 0, stream>>>(tab, rel_index, biasT);
  // QKV: M=131072, N=1536 -> grid 512*6 = 3072 (divisible by 8)
  gemm256<false, 6, EMB><<<3072, 512, 0, stream>>>(
      xb, wq_bf, qkv_bias, (void*)qkv_bf, MROWS, QKVN);
  attn_win<<<BWIN * HEADS, 64, 0, stream>>>(qkv_bf, biasT, flex, ao_bf);
  // proj: M=131072, N=512 -> grid 512*2 = 1024 (divisible by 8)
  gemm256<true, 2, EMB><<<1024, 512, 0, stream>>>(
      ao_bf, wp_bf, proj_b, d_out, MROWS, EMB);
}

// Round 13
// 631.830 us; speedup vs baseline: 1.0096x; 1.0095x over previous
//
#include <hip/hip_runtime.h>

using bf16x8 = __attribute__((ext_vector_type(8))) short;
using f32x4  = __attribute__((ext_vector_type(4))) float;
using f32x16 = __attribute__((ext_vector_type(16))) float;

static constexpr int EMB = 512, HEADS = 16, NTOK = 64, BWIN = 2048;
static constexpr int MROWS = BWIN * NTOK;   // 131072
static constexpr int QKVN  = 3 * EMB;       // 1536

__device__ __forceinline__ float bf2f(unsigned int u) {
  union { unsigned int i; float f; } c; c.i = u << 16; return c.f;
}
__device__ __forceinline__ unsigned short f2bf(float x) {
  union { float f; unsigned int i; } c; c.f = x;
  return (unsigned short)((c.i + 0x7fffu + ((c.i >> 16) & 1u)) >> 16);
}
__device__ __forceinline__ void gload_lds16(const void* g, void* l) {
  __builtin_amdgcn_global_load_lds((const __attribute__((address_space(1))) void*)g,
                                   (__attribute__((address_space(3))) void*)l, 16, 0, 0);
}
__device__ __forceinline__ unsigned int cvt_pk_bf16(float lo, float hi) {
  unsigned int d;
  asm("v_cvt_pk_bf16_f32 %0, %1, %2" : "=v"(d) : "v"(lo), "v"(hi));
  return d;
}

#define BARRIER() __builtin_amdgcn_s_barrier()
#define LGKM0()  do { asm volatile("s_waitcnt lgkmcnt(0)" ::: "memory"); \
                      __builtin_amdgcn_sched_barrier(0); } while (0)
#define VMCNT2() do { asm volatile("s_waitcnt vmcnt(2)" ::: "memory"); \
                      __builtin_amdgcn_sched_barrier(0); } while (0)

// ---------------- xcast: x (fp32) -> bf16, one shot ----------------
__global__ __launch_bounds__(256) void xcast(const float* __restrict__ x,
                                             unsigned short* __restrict__ xb) {
  size_t i = ((size_t)blockIdx.x * 256 + threadIdx.x) * 8;   // 32768 blocks cover 2^26 elems
  float4 a = *(const float4*)(x + i);
  float4 b = *(const float4*)(x + i + 4);
  ushort4 lo = make_ushort4(f2bf(a.x), f2bf(a.y), f2bf(a.z), f2bf(a.w));
  ushort4 hi = make_ushort4(f2bf(b.x), f2bf(b.y), f2bf(b.z), f2bf(b.w));
  *(ushort4*)(xb + i) = lo;
  *(ushort4*)(xb + i + 4) = hi;
}

// ---------------- prep: weights -> bf16, build fused qkv bias ----------------
__global__ void prep_weights(const float* __restrict__ qkv_w, const float* __restrict__ proj_w,
                             const float* __restrict__ q_bias, const float* __restrict__ v_bias,
                             unsigned short* __restrict__ wq, unsigned short* __restrict__ wp,
                             float* __restrict__ qkv_bias) {
  int i = blockIdx.x * 256 + threadIdx.x;          // grid covers 786432 = |qkv_w|
  wq[i] = f2bf(qkv_w[i]);
  if (i < EMB * EMB) wp[i] = f2bf(proj_w[i]);
  if (i < EMB) {
    qkv_bias[i]           = q_bias[i];
    qkv_bias[EMB + i]     = 0.f;                   // k bias is zero in reference
    qkv_bias[2 * EMB + i] = v_bias[i];
  }
}

// ---------------- CPB MLP: 225 positions -> (225,16) raw logits ----------------
__global__ __launch_bounds__(64) void cpb_mlp(const float* __restrict__ tbl,
                        const float* __restrict__ w1, const float* __restrict__ b1,
                        const float* __restrict__ w2, float* __restrict__ tab) {
  __shared__ float hid[512];
  const int p = blockIdx.x, t = threadIdx.x;
  const float t0 = tbl[p * 2], t1 = tbl[p * 2 + 1];
  #pragma unroll
  for (int s = 0; s < 8; ++s) {
    int j = t + s * 64;
    hid[j] = fmaxf(0.f, t0 * w1[j * 2] + t1 * w1[j * 2 + 1] + b1[j]);
  }
  __syncthreads();
  const int h = t >> 2, q = t & 3;
  float sum = 0.f;
  for (int j = q * 128; j < q * 128 + 128; ++j) sum += hid[j] * w2[h * 512 + j];
  sum += __shfl_xor(sum, 1);
  sum += __shfl_xor(sum, 2);
  if (q == 0) tab[p * 16 + h] = sum;
}

// ------- expand TRANSPOSED: biasT[h][kk][q] = 16*sigmoid(tab[rel_index[q][kk]][h]) -------
__global__ void cpb_expand(const float* __restrict__ tab, const int* __restrict__ rel_index,
                           float* __restrict__ biasT) {
  int e = blockIdx.x * 256 + threadIdx.x;   // 65536 total
  int h = e >> 12, ij = e & 4095;
  int kk = ij >> 6, q = ij & 63;
  float x = tab[rel_index[q * 64 + kk] * 16 + h];
  biasT[e] = 16.f / (1.f + __expf(-x));
}

// ---------------- 256x256 8-phase NT GEMM (R4 verbatim: 281us QKV, 7 passing runs) ----------------
template<bool OUT_F32, int NBX, int KT>
__global__ __launch_bounds__(512, 2) void gemm256(const unsigned short* __restrict__ Ap,
    const unsigned short* __restrict__ Bp, const float* __restrict__ bias,
    void* __restrict__ Cp, int M, int N) {
  __shared__ unsigned short As[2][256 * 64];
  __shared__ unsigned short Bs[2][256 * 64];
  constexpr int NT = KT / 64;          // K-tiles (8 for K=512)
  constexpr int NITER = NT / 2;
  const int t = threadIdx.x;
  const int l = t & 63, w = t >> 6;
  const int lr = l & 15, lg = l >> 4;
  const int q8 = gridDim.x >> 3;                       // gridDim.x % 8 == 0
  const int wgid = (blockIdx.x & 7) * q8 + (blockIdx.x >> 3);
  const int n0 = (wgid % NBX) * 256, m0 = (wgid / NBX) * 256;
  const int wm = (w >> 2) * 128, wn = (w & 3) * 64;    // wave's C offset in tile
  const int ha128 = (w >> 2) * 128;                    // wave's A half base row
  const int srow = t >> 3;
  const int scol = ((t & 7) ^ (srow & 7)) << 3;        // inverse-swizzled src col (elems)
  const unsigned short* Abase = Ap + (size_t)m0 * KT;
  const unsigned short* Bbase = Bp + (size_t)n0 * KT;

  f32x4 acc[8][4];
  #pragma unroll
  for (int i = 0; i < 8; ++i)
    #pragma unroll
    for (int j = 0; j < 4; ++j) acc[i][j] = (f32x4){0.f, 0.f, 0.f, 0.f};
  bf16x8 afr[4][2], bfr[4][2];

  auto stage_half = [&](int d, int kt, int half, bool isA) {
    const unsigned short* g = (isA ? Abase : Bbase)
        + (size_t)(half * 128 + srow) * KT + kt * 64 + scol;
    unsigned short* lds = (isA ? &As[d][0] : &Bs[d][0]) + half * 8192 + (t >> 6) * 512;
    gload_lds16(g, lds);                               // rows srow (w*8..w*8+7)
    gload_lds16(g + (size_t)64 * KT, lds + 4096);      // rows srow+64
  };
  auto ldA4 = [&](int d, int mb) {                     // afr <- A frags mb..mb+3, ks 0..1
    #pragma unroll
    for (int m = 0; m < 4; ++m) {
      int row = ha128 + (mb + m) * 16 + lr;
      #pragma unroll
      for (int ks = 0; ks < 2; ++ks)
        afr[m][ks] = *(const bf16x8*)(&As[d][row * 64 + ((((ks << 2) + lg) ^ (lr & 7)) << 3)]);
    }
  };
  auto ldB2 = [&](int d, int nb) {                     // bfr[nb..nb+1] <- B frags
    #pragma unroll
    for (int n = 0; n < 2; ++n) {
      int row = wn + (nb + n) * 16 + lr;
      #pragma unroll
      for (int ks = 0; ks < 2; ++ks)
        bfr[nb + n][ks] = *(const bf16x8*)(&Bs[d][row * 64 + ((((ks << 2) + lg) ^ (lr & 7)) << 3)]);
    }
  };
  auto mfmaQ = [&](int mb, int nb) {                   // 16 MFMA: one C quadrant, K=64
    __builtin_amdgcn_s_setprio(1);
    #pragma unroll
    for (int ks = 0; ks < 2; ++ks)
      #pragma unroll
      for (int m = 0; m < 4; ++m)
        #pragma unroll
        for (int n = 0; n < 2; ++n)
          acc[mb + m][nb + n] = __builtin_amdgcn_mfma_f32_16x16x32_bf16(
              afr[m][ks], bfr[nb + n][ks], acc[mb + m][nb + n], 0, 0, 0);
    __builtin_amdgcn_s_setprio(0);
  };

  // ---- prologue: T0 fully into d0, T1-Ah0 into d1 (mimics ph8 slot) ----
  stage_half(0, 0, 0, true);  stage_half(0, 0, 1, true);
  stage_half(0, 0, 0, false); stage_half(0, 0, 1, false);
  stage_half(1, (NT > 1 ? 1 : 0), 0, true);
  VMCNT2();                                            // T0's 8 loads landed
  BARRIER();

  for (int i = 0; i < NITER; ++i) {
    const int kt1 = 2 * i + 1;                         // always < NT
    const int kt2 = (2 * i + 2 < NT) ? 2 * i + 2 : NT - 1;   // clamped (tail garbage)
    const int kt3 = (2 * i + 3 < NT) ? 2 * i + 3 : NT - 1;
    // PH1: ds A(d0,mf0-3)+B(d0,nf0-1); stage d1<-T(kt1)-Ah1
    ldA4(0, 0); ldB2(0, 0);
    stage_half(1, kt1, 1, true);
    BARRIER(); LGKM0(); mfmaQ(0, 0); BARRIER();
    // PH2: ds B(d0,nf2-3); stage d1<-T(kt1)-Bh0
    ldB2(0, 2);
    stage_half(1, kt1, 0, false);
    BARRIER(); LGKM0(); mfmaQ(0, 2); BARRIER();
    // PH3: ds A(d0,mf4-7); stage d1<-T(kt1)-Bh1   (d0 fully consumed after this)
    ldA4(0, 4);
    stage_half(1, kt1, 1, false);
    BARRIER(); LGKM0(); mfmaQ(4, 2); BARRIER();
    // PH4: stage d0<-T(kt2)-Ah0; GATE vmcnt(2): T(kt1) all landed for ph5-8
    stage_half(0, kt2, 0, true);
    VMCNT2(); BARRIER(); mfmaQ(4, 0); BARRIER();
    // PH5: ds A(d1,mf0-3)+B(d1,nf0-1); stage d0<-T(kt2)-Ah1
    ldA4(1, 0); ldB2(1, 0);
    stage_half(0, kt2, 1, true);
    BARRIER(); LGKM0(); mfmaQ(0, 0); BARRIER();
    // PH6: ds B(d1,nf2-3); stage d0<-T(kt2)-Bh0
    ldB2(1, 2);
    stage_half(0, kt2, 0, false);
    BARRIER(); LGKM0(); mfmaQ(0, 2); BARRIER();
    // PH7: ds A(d1,mf4-7); stage d0<-T(kt2)-Bh1   (d1 fully consumed after this)
    ldA4(1, 4);
    stage_half(0, kt2, 1, false);
    BARRIER(); LGKM0(); mfmaQ(4, 2); BARRIER();
    // PH8: stage d1<-T(kt3)-Ah0; GATE vmcnt(2): T(kt2) all landed for next iter
    stage_half(1, kt3, 0, true);
    VMCNT2(); BARRIER(); mfmaQ(4, 0); BARRIER();
  }

  // ---- epilogue: C = acc + bias ----
  #pragma unroll
  for (int mf = 0; mf < 8; ++mf)
    #pragma unroll
    for (int nf = 0; nf < 4; ++nf)
      #pragma unroll
      for (int r = 0; r < 4; ++r) {
        int mm = m0 + wm + mf * 16 + lg * 4 + r;
        int nn = n0 + wn + nf * 16 + lr;
        float v = acc[mf][nf][r] + bias[nn];
        if (OUT_F32) ((float*)Cp)[(size_t)mm * N + nn] = v;
        else ((unsigned short*)Cp)[(size_t)mm * N + nn] = f2bf(v);
      }
}

// ------------- fused window attention v5: 4 heads/block, coalesced K/Q staging -------------
// Block = 4 waves = heads 4p..4p+3 of window b. K+Q for the 4 heads (64 tok x 2 x
// 256B = 32KB) staged via 8 fully-coalesced gload_lds per wave; physical 16B slot
// = logical ^ (tok&15), inverse swizzle on the per-lane global SOURCE (rule #21)
// -> fragment reads (stride 512B) drop from 32-way to 4-way bank aliasing.
// ONE __syncthreads (full drain — no counted-vmcnt schedule, zero race surface).
// V path, norm, QK^T/softmax/pack/PV math all R12/v2-verbatim. LDS 48KB ->
// 3 blocks/CU = 12 waves/CU (occupancy parity with v2).
__global__ __launch_bounds__(256, 3) void attn_win4(const unsigned short* __restrict__ qkv,
    const float* __restrict__ biasT, const float* __restrict__ flex,
    unsigned short* __restrict__ aout) {
  __shared__ __align__(16) unsigned short kq[16384];      // [tok][sec][phys-slot] 32KB
  __shared__ __align__(16) unsigned short vTall[4][2048]; // per-wave vT[32][64] 16KB
  const int t = threadIdx.x;
  const int l = t & 63, w = t >> 6;
  const int lq = l & 31, hi = l >> 5;
  // XCD-bijective swizzle (grid 8192 % 8 == 0): a window's 4 blocks -> same XCD
  const int g = (blockIdx.x & 7) * (gridDim.x >> 3) + (blockIdx.x >> 3);
  const int b = g >> 2;
  const int p = g & 3;
  const int h = p * 4 + w;
  const unsigned short* base = qkv + (size_t)b * NTOK * QKVN;
  const float scale = __expf(fminf(flex[h], 4.6051701860f));   // min(flex, ln 100)

  // early V load (direct global, 64B/lane — best-coalesced stream, as v2)
  const uint4* vp = (const uint4*)(base + (size_t)l * QKVN + 2 * EMB + h * 32);
  uint4 v0 = vp[0], v1 = vp[1], v2 = vp[2], v3 = vp[3];

  // ---- stage K+Q for heads 4p..4p+3 (coalesced; inverse-swizzled source) ----
  // linear 16B-slot sl = (w*8+i)*64 + lane: tok = sl>>5, sec = (sl>>4)&1 (0=q,1=k),
  // phys = sl&15 holds logical slot log = phys ^ (tok&15).
  #pragma unroll
  for (int i = 0; i < 8; ++i) {
    int sl  = (w * 8 + i) * 64 + l;
    int tok = sl >> 5, sec = (sl >> 4) & 1, phys = sl & 15;
    int log = phys ^ (tok & 15);
    gload_lds16(base + (size_t)tok * QKVN + (sec ? EMB : 0) + p * 128 + log * 8,
                kq + (size_t)(w * 8 + i) * 512);
  }

  // ---- vT[d][tok] from preloaded V regs (same-wave region, 16B-slot XOR swizzle) ----
  unsigned short* vT = vTall[w];
  {
    unsigned int wd[16] = {v0.x, v0.y, v0.z, v0.w, v1.x, v1.y, v1.z, v1.w,
                           v2.x, v2.y, v2.z, v2.w, v3.x, v3.y, v3.z, v3.w};
    #pragma unroll
    for (int d = 0; d < 32; ++d) {
      unsigned short val = (d & 1) ? (unsigned short)(wd[d >> 1] >> 16)
                                   : (unsigned short)(wd[d >> 1] & 0xffffu);
      vT[d * 64 + (((l >> 3) ^ (d & 7)) << 3) + (l & 7)] = val;
    }
  }
  __syncthreads();                               // drains gload_lds + ds_writes (full)

  // ---- K and Q fragments from LDS, L2-normalized in-register (math == v2) ----
  bf16x8 kfr[2][2], qfr[2][2];                   // [tok-frag][d-chunk]
  #pragma unroll
  for (int f = 0; f < 2; ++f) {
    #pragma unroll
    for (int which = 0; which < 2; ++which) {    // 0 = K (sec=1), 1 = Q (sec=0)
      const int tok = f * 32 + lq;
      const int sec = which ? 0 : 1;
      const unsigned short* row = kq + tok * 256 + sec * 128;   // ushort units
      const int ls0 = w * 4 + hi;                // chunk0 logical slot
      const int ls1 = w * 4 + 2 + hi;            // chunk1 logical slot
      uint4 r0 = *(const uint4*)(row + ((ls0 ^ (tok & 15)) << 3));
      uint4 r1 = *(const uint4*)(row + ((ls1 ^ (tok & 15)) << 3));
      unsigned int wd[8] = {r0.x, r0.y, r0.z, r0.w, r1.x, r1.y, r1.z, r1.w};
      float fv[16];
      #pragma unroll
      for (int e = 0; e < 8; ++e) {
        fv[2 * e]     = bf2f(wd[e] & 0xffffu);
        fv[2 * e + 1] = bf2f(wd[e] >> 16);
      }
      float ss = 0.f;
      #pragma unroll
      for (int e = 0; e < 16; ++e) ss += fv[e] * fv[e];
      ss += __shfl_xor(ss, 32);                  // partner holds the other 16 dims
      float inv = (which ? scale : 1.f) / fmaxf(sqrtf(ss), 1e-12f);
      bf16x8 f0, f1;
      #pragma unroll
      for (int e = 0; e < 8; ++e) {
        f0[e] = (short)f2bf(fv[e] * inv);        // d-chunk 0 (d = hi*8+e)
        f1[e] = (short)f2bf(fv[8 + e] * inv);    // d-chunk 1 (d = 16+hi*8+e)
      }
      if (which) { qfr[f][0] = f0; qfr[f][1] = f1; }
      else       { kfr[f][0] = f0; kfr[f][1] = f1; }
    }
  }

  // ---- vT B-fragments (shared by both q-halves): conflict-free swizzled b128 ----
  bf16x8 bv[4];
  #pragma unroll
  for (int c = 0; c < 4; ++c)
    bv[c] = *(const bf16x8*)(&vT[lq * 64 + ((((2 * c + hi) ^ (lq & 7))) << 3)]);

  const f32x16 z16 = (f32x16)(0.f);

  // ---- per q-half: QK^T (swapped) -> bias -> softmax -> pack -> PV -> store ----
  #pragma unroll
  for (int qf = 0; qf < 2; ++qf) {
    // S^T[kk][q]: kk-frag kf in rows, q = lane&31
    f32x16 s0 = __builtin_amdgcn_mfma_f32_32x32x16_bf16(kfr[0][0], qfr[qf][0], z16, 0, 0, 0);
    s0 = __builtin_amdgcn_mfma_f32_32x32x16_bf16(kfr[0][1], qfr[qf][1], s0, 0, 0, 0);
    f32x16 s1 = __builtin_amdgcn_mfma_f32_32x32x16_bf16(kfr[1][0], qfr[qf][0], z16, 0, 0, 0);
    s1 = __builtin_amdgcn_mfma_f32_32x32x16_bf16(kfr[1][1], qfr[qf][1], s1, 0, 0, 0);

    // p[kf*16+r] = S^T + biasT[h][kk][q],  kk = kf*32 + (r&3) + 8*(r>>2) + 4*hi
    float p2[32];
    const float* bt = biasT + (size_t)h * 4096 + qf * 32 + lq;
    #pragma unroll
    for (int r = 0; r < 16; ++r) {
      int kkb = (r & 3) + 8 * (r >> 2) + 4 * hi;
      p2[r]      = s0[r] + bt[kkb * 64];
      p2[16 + r] = s1[r] + bt[(32 + kkb) * 64];
    }
    float mx = p2[0];
    #pragma unroll
    for (int e = 1; e < 32; ++e) mx = fmaxf(mx, p2[e]);
    mx = fmaxf(mx, __shfl_xor(mx, 32));
    float sum = 0.f;
    #pragma unroll
    for (int e = 0; e < 32; ++e) { p2[e] = __expf(p2[e] - mx); sum += p2[e]; }
    sum += __shfl_xor(sum, 32);
    const float inv = 1.f / sum;
    #pragma unroll
    for (int e = 0; e < 32; ++e) p2[e] *= inv;   // normalized P -> no O epilogue scale

    // pack kk-pairs to bf16 dwords; swap halves; assemble PV A-frags
    unsigned int wp_[2][8], sw[2][8];
    #pragma unroll
    for (int kf = 0; kf < 2; ++kf)
      #pragma unroll
      for (int m = 0; m < 8; ++m) {
        wp_[kf][m] = cvt_pk_bf16(p2[kf * 16 + 2 * m], p2[kf * 16 + 2 * m + 1]);
        sw[kf][m]  = (unsigned int)__builtin_amdgcn_ds_bpermute(
                        ((l ^ 32) & 63) << 2, (int)wp_[kf][m]);
      }
    f32x16 oacc = z16;
    #pragma unroll
    for (int c = 0; c < 4; ++c) {
      const int kf = c >> 1, mlo = (c & 1) * 4;
      unsigned int d0 = hi ? sw[kf][mlo + 2] : wp_[kf][mlo + 0];
      unsigned int d1 = hi ? sw[kf][mlo + 3] : wp_[kf][mlo + 1];
      unsigned int d2 = hi ? wp_[kf][mlo + 2] : sw[kf][mlo + 0];
      unsigned int d3 = hi ? wp_[kf][mlo + 3] : sw[kf][mlo + 1];
      union { uint4 u; bf16x8 v; } pa;
      pa.u = make_uint4(d0, d1, d2, d3);
      oacc = __builtin_amdgcn_mfma_f32_32x32x16_bf16(pa.v, bv[c], oacc, 0, 0, 0);
    }
    // O[q][d]: q = qf*32 + (r&3)+8*(r>>2)+4*hi, d = lane&31 (64B contiguous stores)
    #pragma unroll
    for (int r = 0; r < 16; ++r) {
      int q = qf * 32 + (r & 3) + 8 * (r >> 2) + 4 * hi;
      aout[(size_t)(b * NTOK + q) * EMB + h * 32 + lq] = f2bf(oacc[r]);
    }
  }
}

// ---------------- launch ----------------
extern "C" void kernel_launch(void* const* d_in, const int* in_sizes, int n_in,
                              void* d_out, int out_size, void* d_ws, size_t ws_size,
                              hipStream_t stream) {
  const float* x         = (const float*)d_in[0];
  const float* qkv_w     = (const float*)d_in[1];
  const float* q_bias    = (const float*)d_in[2];
  const float* v_bias    = (const float*)d_in[3];
  const float* flex      = (const float*)d_in[4];
  const float* cpb_w1    = (const float*)d_in[5];
  const float* cpb_b1    = (const float*)d_in[6];
  const float* cpb_w2    = (const float*)d_in[7];
  const float* proj_w    = (const float*)d_in[8];
  const float* proj_b    = (const float*)d_in[9];
  const float* rel_table = (const float*)d_in[10];
  const int*   rel_index = (const int*)d_in[11];

  char* ws = (char*)d_ws;
  unsigned short* qkv_bf = (unsigned short*)(ws + 0);                  // 402,653,184 B
  // xb (bf16 x) and ao_bf ALIAS: xb dies when the QKV GEMM finishes; ao_bf is
  // born at attn_win4. Both are 134,217,728 B and fully rewritten every call.
  unsigned short* xb     = (unsigned short*)(ws + 402653184ull);
  unsigned short* ao_bf  = (unsigned short*)(ws + 402653184ull);
  unsigned short* wq_bf  = (unsigned short*)(ws + 536870912ull);       //   1,572,864 B
  unsigned short* wp_bf  = (unsigned short*)(ws + 538443776ull);       //     524,288 B
  float* qkv_bias        = (float*)(ws + 538968064ull);                //       6,144 B
  float* tab             = (float*)(ws + 538974208ull);                //      14,400 B
  float* biasT           = (float*)(ws + 538988608ull);                //     262,144 B

  xcast<<<32768, 256, 0, stream>>>(x, xb);
  prep_weights<<<3072, 256, 0, stream>>>(qkv_w, proj_w, q_bias, v_bias, wq_bf, wp_bf, qkv_bias);
  cpb_mlp<<<225, 64, 0, stream>>>(rel_table, cpb_w1, cpb_b1, cpb_w2, tab);
  cpb_expand<<<256, 256, 0, stream>>>(tab, rel_index, biasT);
  // QKV: M=131072, N=1536 -> grid 512*6 = 3072 (divisible by 8)
  gemm256<false, 6, EMB><<<3072, 512, 0, stream>>>(
      xb, wq_bf, qkv_bias, (void*)qkv_bf, MROWS, QKVN);
  attn_win4<<<BWIN * 4, 256, 0, stream>>>(qkv_bf, biasT, flex, ao_bf);
  // proj: M=131072, N=512 -> grid 512*2 = 1024 (divisible by 8)
  gemm256<true, 2, EMB><<<1024, 512, 0, stream>>>(
      ao_bf, wp_bf, proj_b, d_out, MROWS, EMB);
}